// Round 1
// 477.705 us; speedup vs baseline: 1.2616x; 1.2616x over previous
//
#include <hip/hip_runtime.h>
#include <hip/hip_bf16.h>
#include <math.h>

// ---------------- problem constants ----------------
#define B_ROWS 1024
#define EMB    512
#define NCLS   100000
#define SCALE_ 64.0f
// margin = 0.5
#define COS_M 0.8775825618903728f
#define SIN_M 0.479425538604203f
#define TH_C  (-0.8775825618903728f)
#define MM_C  0.2397127693021015f

// ---------------- GEMM tiling ----------------
#define BM 128
#define BN 128
#define BK 32
#define NTILES 782   // ceil(100000/128)
#define KCHUNKS 16   // 512/32

typedef __attribute__((ext_vector_type(8))) short bf16x8;   // 8 bf16 = 4 VGPRs
typedef __attribute__((ext_vector_type(4))) float f32x4;

typedef __attribute__((address_space(1))) const unsigned int GLP;
typedef __attribute__((address_space(3))) unsigned int LDP;

__device__ __forceinline__ float bf2f(short u) {
  unsigned int x = ((unsigned int)(unsigned short)u) << 16;
  return __builtin_bit_cast(float, x);
}
__device__ __forceinline__ short f2bf(float f) {   // RNE fp32 -> bf16
  unsigned int u = __builtin_bit_cast(unsigned int, f);
  u += 0x7FFF + ((u >> 16) & 1);
  return (short)(u >> 16);
}

// async global->LDS, 16B/lane; LDS dest = wave-uniform base, lane i lands at base + i*16
__device__ __forceinline__ void load16(const void* g, void* l) {
  __builtin_amdgcn_global_load_lds((GLP*)g, (LDP*)l, 16, 0, 0);
}

// ---------------- setup: zero accums, detect label width AND input dtype ----------------
__global__ void setup_kernel(const void* __restrict__ emb, const int* __restrict__ labels,
                             float* __restrict__ row_sum, float* __restrict__ accum,
                             int* __restrict__ flag, int* __restrict__ dflag) {
  const int t = threadIdx.x;           // 512 threads
  row_sum[t] = 0.f;
  row_sum[t + 512] = 0.f;
  if (t == 0) *accum = 0.f;

  // ---- input dtype probe (wave 0): ssq of emb row 0 read AS bf16.
  // bf16 data -> ~512 (sane). fp32 data -> low-half shorts have random exponents -> inf/NaN whp.
  if (t < 64) {
    bf16x8 v = *(const bf16x8*)((const short*)emb + t * 8);
    float s = 0.f;
    #pragma unroll
    for (int j = 0; j < 8; ++j) { float f = bf2f(v[j]); s += f * f; }
    #pragma unroll
    for (int off = 1; off < 64; off <<= 1) s += __shfl_xor(s, off);
    if (t == 0) *dflag = (s < 1e8f) ? 1 : 0;       // NaN/inf compare false -> fp32
  }

  // ---- label width probe: high words if int64 are all zero
  int v = labels[2 * t + 1];
  #pragma unroll
  for (int off = 1; off < 64; off <<= 1) v |= __shfl_xor(v, off);
  __shared__ int red[8];
  if ((t & 63) == 0) red[t >> 6] = v;
  __syncthreads();
  if (t == 0) {
    int o = 0;
    #pragma unroll
    for (int i = 0; i < 8; ++i) o |= red[i];
    *flag = (o == 0) ? 1 : 0;          // 1 => int64 labels (read low word at 2*r)
  }
}

// ---------------- inverse L2 norms + (optional) normalized-bf16 write-back ----------------
__global__ void normconv_kernel(const void* __restrict__ emb, const void* __restrict__ wgt,
                                const int* __restrict__ dflag,
                                float* __restrict__ inv_e, float* __restrict__ inv_w,
                                short* __restrict__ An, short* __restrict__ Wn,
                                const int do_conv) {
  const int wave = threadIdx.x >> 6;
  const int lane = threadIdx.x & 63;
  const int row = blockIdx.x * 4 + wave;
  int r;
  const void* base;
  float* dst;
  short* out;
  if (row < B_ROWS) { r = row; base = emb; dst = inv_e + row; out = An + (size_t)row * EMB; }
  else {
    r = row - B_ROWS;
    if (r >= NCLS) return;
    base = wgt; dst = inv_w + r; out = Wn + (size_t)r * EMB;
  }
  float f[8];
  if (*dflag) {
    const short* p = (const short*)base + (size_t)r * EMB;
    bf16x8 v = *(const bf16x8*)(p + lane * 8);
    #pragma unroll
    for (int j = 0; j < 8; ++j) f[j] = bf2f(v[j]);
  } else {
    const float* p = (const float*)base + (size_t)r * EMB;
    f32x4 x = *(const f32x4*)(p + lane * 8);
    f32x4 y = *(const f32x4*)(p + lane * 8 + 4);
    #pragma unroll
    for (int j = 0; j < 4; ++j) { f[j] = x[j]; f[j + 4] = y[j]; }
  }
  float s = 0.f;
  #pragma unroll
  for (int j = 0; j < 8; ++j) s += f[j] * f[j];
  #pragma unroll
  for (int off = 1; off < 64; off <<= 1) s += __shfl_xor(s, off);
  const float inv = 1.f / fmaxf(sqrtf(s), 1e-12f);
  if (lane == 0) *dst = inv;
  if (do_conv) {
    bf16x8 o;
    #pragma unroll
    for (int j = 0; j < 8; ++j) o[j] = f2bf(f[j] * inv);
    *(bf16x8*)(out + lane * 8) = o;
  }
}

// ---------------- FAST PATH: pure-bf16 NT-GEMM on pre-normalized inputs ----------------
__global__ __launch_bounds__(256, 3) void arc_gemm_fast(
    const short* __restrict__ A, const short* __restrict__ W,
    const int* __restrict__ labels, const int* __restrict__ flag,
    float* __restrict__ row_sum, float* __restrict__ lablogit) {
  __shared__ short As[BM * BK];     // 8 KB, row-major [row][k], row stride 64 B
  __shared__ short Bs[BN * BK];     // 8 KB
  __shared__ int   sh_lab[BM];
  __shared__ float sh_sum[BM][2];

  const int tid  = threadIdx.x;
  const int wave = tid >> 6;
  const int lane = tid & 63;
  const int wy = wave >> 1;         // 2x2 wave grid, each wave 64x64
  const int wx = wave & 1;
  const int lr = lane & 15;
  const int lk = lane >> 4;
  const int mBase = blockIdx.x * BM;
  const int nBase = blockIdx.y * BN;

  const int srow  = lane >> 2;      // staging: 16 rows per wave-instr
  const int sbyte = (lane & 3) * 16;

  f32x4 zero = {0.f, 0.f, 0.f, 0.f};
  f32x4 acc[4][4];
  #pragma unroll
  for (int i = 0; i < 4; ++i)
    #pragma unroll
    for (int j = 0; j < 4; ++j) acc[i][j] = zero;

  const char* Ab = (const char*)A;   // bf16 row stride 1024 B
  const char* Wb = (const char*)W;

  for (int kc = 0; kc < KCHUNKS; ++kc) {
    __syncthreads();
    const size_t koff = (size_t)kc * 64 + sbyte;
    #pragma unroll
    for (int it = 0; it < 2; ++it) {
      const int c = wave + it * 4;                  // chunk = 16 rows = 1024 B of LDS
      const int ar = mBase + c * 16 + srow;         // always < 1024
      load16(Ab + (size_t)ar * 1024 + koff, (char*)As + (size_t)c * 1024);
      int br = nBase + c * 16 + srow;
      if (br >= NCLS) br = NCLS - 1;                // clamp; masked in epilogue
      load16(Wb + (size_t)br * 1024 + koff, (char*)Bs + (size_t)c * 1024);
    }
    __syncthreads();                                // drains vmcnt/lgkmcnt before use
    bf16x8 af[4], bfr[4];
    #pragma unroll
    for (int mi = 0; mi < 4; ++mi)
      af[mi] = *(const bf16x8*)(As + ((wy * 64 + mi * 16 + lr) * BK + lk * 8));
    #pragma unroll
    for (int ni = 0; ni < 4; ++ni)
      bfr[ni] = *(const bf16x8*)(Bs + ((wx * 64 + ni * 16 + lr) * BK + lk * 8));
    #pragma unroll
    for (int mi = 0; mi < 4; ++mi)
      #pragma unroll
      for (int ni = 0; ni < 4; ++ni)
        acc[mi][ni] = __builtin_amdgcn_mfma_f32_16x16x32_bf16(af[mi], bfr[ni], acc[mi][ni], 0, 0, 0);
  }

  // ---- epilogue (cos = accumulator directly; inputs pre-normalized) ----
  __syncthreads();
  if (tid < BM) {
    const int r = mBase + tid;
    const int f = *flag;
    sh_lab[tid] = labels[f ? (size_t)(2 * r) : (size_t)r];
  }
  __syncthreads();

  #pragma unroll
  for (int mi = 0; mi < 4; ++mi) {
    #pragma unroll
    for (int reg = 0; reg < 4; ++reg) {
      const int lrow = wy * 64 + mi * 16 + lk * 4 + reg;   // C/D: row=(lane>>4)*4+reg
      const int grow = mBase + lrow;
      const int lab = sh_lab[lrow];
      float s = 0.f;
      #pragma unroll
      for (int ni = 0; ni < 4; ++ni) {
        const int gcol = nBase + wx * 64 + ni * 16 + lr;   // C/D: col=lane&15
        if (gcol < NCLS) {
          const float cosv = acc[mi][ni][reg];
          float logit;
          if (gcol == lab) {
            const float sine = sqrtf(fmaxf(1.f - cosv * cosv, 0.f));
            float phi = cosv * COS_M - sine * SIN_M;
            phi = (cosv > TH_C) ? phi : (cosv - MM_C);
            logit = SCALE_ * phi;
            lablogit[grow] = logit;                        // unique writer grid-wide
          } else {
            logit = SCALE_ * cosv;
          }
          s += __expf(logit - SCALE_);                     // offset-64 softmax partial
        }
      }
      #pragma unroll
      for (int off = 1; off < 16; off <<= 1) s += __shfl_xor(s, off);
      if (lr == 0) sh_sum[lrow][wx] = s;
    }
  }
  __syncthreads();
  if (tid < BM)
    atomicAdd(&row_sum[mBase + tid], sh_sum[tid][0] + sh_sum[tid][1]);
}

// ---------------- FALLBACK: fused NT-GEMM with in-loop dtype staging ----------------
__global__ __launch_bounds__(256, 3) void arc_gemm(
    const void* __restrict__ A, const void* __restrict__ W,
    const float* __restrict__ inv_e, const float* __restrict__ inv_w,
    const int* __restrict__ labels, const int* __restrict__ flag,
    const int* __restrict__ dflag,
    float* __restrict__ row_sum, float* __restrict__ lablogit) {
  __shared__ short As[BM * BK];
  __shared__ short Bs[BN * BK];
  __shared__ int   sh_lab[BM];
  __shared__ float sh_sum[BM][2];

  const int tid  = threadIdx.x;
  const int wave = tid >> 6;
  const int lane = tid & 63;
  const int wy = wave >> 1;
  const int wx = wave & 1;
  const int lr = lane & 15;
  const int lk = lane >> 4;
  const int mBase = blockIdx.x * BM;
  const int nBase = blockIdx.y * BN;
  const int isbf16 = *dflag;

  const int srow  = lane >> 2;
  const int sbyte = (lane & 3) * 16;

  f32x4 zero = {0.f, 0.f, 0.f, 0.f};
  f32x4 acc[4][4];
  #pragma unroll
  for (int i = 0; i < 4; ++i)
    #pragma unroll
    for (int j = 0; j < 4; ++j) acc[i][j] = zero;

  const char*  Ab = (const char*)A;
  const char*  Wb = (const char*)W;
  const float* Af = (const float*)A;
  const float* Wf = (const float*)W;

  for (int kc = 0; kc < KCHUNKS; ++kc) {
    __syncthreads();
    if (isbf16) {
      const size_t koff = (size_t)kc * 64 + sbyte;
      #pragma unroll
      for (int it = 0; it < 2; ++it) {
        const int c = wave + it * 4;
        const int ar = mBase + c * 16 + srow;
        load16(Ab + (size_t)ar * 1024 + koff, (char*)As + (size_t)c * 1024);
        int br = nBase + c * 16 + srow;
        if (br >= NCLS) br = NCLS - 1;
        load16(Wb + (size_t)br * 1024 + koff, (char*)Bs + (size_t)c * 1024);
      }
    } else {
      #pragma unroll
      for (int p = 0; p < 2; ++p) {
        const int u   = p * 256 + tid;
        const int row = u >> 2;
        const int seg = u & 3;
        const float* ga = Af + ((size_t)(mBase + row) * EMB + kc * 32 + seg * 8);
        f32x4 x = *(const f32x4*)ga;
        f32x4 y = *(const f32x4*)(ga + 4);
        bf16x8 tpack;
        #pragma unroll
        for (int j = 0; j < 4; ++j) { tpack[j] = f2bf(x[j]); tpack[j + 4] = f2bf(y[j]); }
        *(bf16x8*)(As + row * BK + seg * 8) = tpack;
        int br = nBase + row;
        if (br >= NCLS) br = NCLS - 1;
        const float* gb = Wf + ((size_t)br * EMB + kc * 32 + seg * 8);
        x = *(const f32x4*)gb;
        y = *(const f32x4*)(gb + 4);
        #pragma unroll
        for (int j = 0; j < 4; ++j) { tpack[j] = f2bf(x[j]); tpack[j + 4] = f2bf(y[j]); }
        *(bf16x8*)(Bs + row * BK + seg * 8) = tpack;
      }
    }
    __syncthreads();
    bf16x8 af[4], bfr[4];
    #pragma unroll
    for (int mi = 0; mi < 4; ++mi)
      af[mi] = *(const bf16x8*)(As + ((wy * 64 + mi * 16 + lr) * BK + lk * 8));
    #pragma unroll
    for (int ni = 0; ni < 4; ++ni)
      bfr[ni] = *(const bf16x8*)(Bs + ((wx * 64 + ni * 16 + lr) * BK + lk * 8));
    #pragma unroll
    for (int mi = 0; mi < 4; ++mi)
      #pragma unroll
      for (int ni = 0; ni < 4; ++ni)
        acc[mi][ni] = __builtin_amdgcn_mfma_f32_16x16x32_bf16(af[mi], bfr[ni], acc[mi][ni], 0, 0, 0);
  }

  __syncthreads();
  if (tid < BM) {
    const int r = mBase + tid;
    const int f = *flag;
    sh_lab[tid] = labels[f ? (size_t)(2 * r) : (size_t)r];
  }
  __syncthreads();

  #pragma unroll
  for (int mi = 0; mi < 4; ++mi) {
    #pragma unroll
    for (int reg = 0; reg < 4; ++reg) {
      const int lrow = wy * 64 + mi * 16 + lk * 4 + reg;
      const int grow = mBase + lrow;
      const float ie = inv_e[grow];
      const int lab = sh_lab[lrow];
      float s = 0.f;
      #pragma unroll
      for (int ni = 0; ni < 4; ++ni) {
        const int gcol = nBase + wx * 64 + ni * 16 + lr;
        if (gcol < NCLS) {
          const float cosv = acc[mi][ni][reg] * ie * inv_w[gcol];
          float logit;
          if (gcol == lab) {
            const float sine = sqrtf(fmaxf(1.f - cosv * cosv, 0.f));
            float phi = cosv * COS_M - sine * SIN_M;
            phi = (cosv > TH_C) ? phi : (cosv - MM_C);
            logit = SCALE_ * phi;
            lablogit[grow] = logit;
          } else {
            logit = SCALE_ * cosv;
          }
          s += __expf(logit - SCALE_);
        }
      }
      #pragma unroll
      for (int off = 1; off < 16; off <<= 1) s += __shfl_xor(s, off);
      if (lr == 0) sh_sum[lrow][wx] = s;
    }
  }
  __syncthreads();
  if (tid < BM)
    atomicAdd(&row_sum[mBase + tid], sh_sum[tid][0] + sh_sum[tid][1]);
}

// ---------------- per-row loss -> mean ----------------
__global__ void loss_kernel(const float* __restrict__ row_sum,
                            const float* __restrict__ lablogit,
                            float* __restrict__ accum) {
  const int r = blockIdx.x * 128 + threadIdx.x;
  float loss = SCALE_ + logf(row_sum[r]) - lablogit[r];
  #pragma unroll
  for (int off = 1; off < 64; off <<= 1) loss += __shfl_xor(loss, off);
  __shared__ float rs[2];
  if ((threadIdx.x & 63) == 0) rs[threadIdx.x >> 6] = loss;
  __syncthreads();
  if (threadIdx.x == 0) atomicAdd(accum, rs[0] + rs[1]);
}

__global__ void finalize_kernel(const float* __restrict__ accum, float* __restrict__ out) {
  out[0] = accum[0] * (1.0f / 1024.0f);   // reference output is float32
}

// ---------------- launch ----------------
extern "C" void kernel_launch(void* const* d_in, const int* in_sizes, int n_in,
                              void* d_out, int out_size, void* d_ws, size_t ws_size,
                              hipStream_t stream) {
  const void* emb   = d_in[0];          // [1024][512]  bf16 or fp32 (auto-detected)
  const void* wgt   = d_in[1];          // [100000][512]
  const int* labels = (const int*)d_in[2];   // int32 or int64 (auto-detected)
  float* out = (float*)d_out;

  // fast-path workspace: pre-normalized bf16 copies of W and A
  const size_t WN_SHORTS = (size_t)NCLS * EMB;        // 51,200,000
  const size_t AN_SHORTS = (size_t)B_ROWS * EMB;      // 524,288
  const size_t FAST_NEED = (WN_SHORTS + AN_SHORTS) * 2 + 103075u * 4;  // ~103.9 MB

  if (ws_size >= FAST_NEED) {
    short* Wn = (short*)d_ws;
    short* An = Wn + WN_SHORTS;
    float* tail     = (float*)(An + AN_SHORTS);
    float* inv_e    = tail;               // 1024 (unused by fast gemm; kept for debug)
    float* inv_w    = tail + 1024;        // 100000
    float* lablogit = tail + 101024;      // 1024
    float* row_sum  = tail + 102048;      // 1024
    float* accum    = tail + 103072;      // 1
    int*   flag     = (int*)(tail + 103073);
    int*   dflag    = (int*)(tail + 103074);

    setup_kernel<<<1, 512, 0, stream>>>(emb, labels, row_sum, accum, flag, dflag);
    normconv_kernel<<<(B_ROWS + NCLS) / 4, 256, 0, stream>>>(
        emb, wgt, dflag, inv_e, inv_w, An, Wn, 1);
    dim3 grid(8, NTILES);
    arc_gemm_fast<<<grid, 256, 0, stream>>>(An, Wn, labels, flag, row_sum, lablogit);
    loss_kernel<<<8, 128, 0, stream>>>(row_sum, lablogit, accum);
    finalize_kernel<<<1, 1, 0, stream>>>(accum, out);
  } else {
    float* ws       = (float*)d_ws;
    float* inv_e    = ws;                 // 1024
    float* inv_w    = ws + 1024;          // 100000
    float* lablogit = ws + 101024;        // 1024
    float* row_sum  = ws + 102048;        // 1024
    float* accum    = ws + 103072;        // 1
    int*   flag     = (int*)(ws + 103073);
    int*   dflag    = (int*)(ws + 103074);

    setup_kernel<<<1, 512, 0, stream>>>(emb, labels, row_sum, accum, flag, dflag);
    normconv_kernel<<<(B_ROWS + NCLS) / 4, 256, 0, stream>>>(
        emb, wgt, dflag, inv_e, inv_w, (short*)inv_e, (short*)inv_e, 0);
    dim3 grid(8, NTILES);
    arc_gemm<<<grid, 256, 0, stream>>>(emb, wgt, inv_e, inv_w, labels, flag, dflag, row_sum, lablogit);
    loss_kernel<<<8, 128, 0, stream>>>(row_sum, lablogit, accum);
    finalize_kernel<<<1, 1, 0, stream>>>(accum, out);
  }
}

// Round 2
// 465.297 us; speedup vs baseline: 1.2952x; 1.0267x over previous
//
#include <hip/hip_runtime.h>
#include <hip/hip_bf16.h>
#include <math.h>

// ---------------- problem constants ----------------
#define B_ROWS 1024
#define EMB    512
#define NCLS   100000
#define SCALE_ 64.0f
// margin = 0.5
#define COS_M 0.8775825618903728f
#define SIN_M 0.479425538604203f
#define TH_C  (-0.8775825618903728f)
#define MM_C  0.2397127693021015f

// ---------------- GEMM tiling ----------------
#define BM 128
#define BN 128
#define BK 32
#define NTILES 782   // ceil(100000/128)
#define KCHUNKS 16   // 512/32

typedef __attribute__((ext_vector_type(8))) short bf16x8;   // 8 bf16 = 4 VGPRs
typedef __attribute__((ext_vector_type(4))) short s16x4;
typedef __attribute__((ext_vector_type(4))) float f32x4;

typedef __attribute__((address_space(1))) const unsigned int GLP;
typedef __attribute__((address_space(3))) unsigned int LDP;

__device__ __forceinline__ float bf2f(short u) {
  unsigned int x = ((unsigned int)(unsigned short)u) << 16;
  return __builtin_bit_cast(float, x);
}
__device__ __forceinline__ short f2bf(float f) {   // RNE fp32 -> bf16
  unsigned int u = __builtin_bit_cast(unsigned int, f);
  u += 0x7FFF + ((u >> 16) & 1);
  return (short)(u >> 16);
}

// async global->LDS, 16B/lane; LDS dest = wave-uniform base, lane i lands at base + i*16
__device__ __forceinline__ void load16(const void* g, void* l) {
  __builtin_amdgcn_global_load_lds((GLP*)g, (LDP*)l, 16, 0, 0);
}

// ---------------- setup: zero accums, detect label width AND input dtype ----------------
__global__ void setup_kernel(const void* __restrict__ emb, const int* __restrict__ labels,
                             float* __restrict__ row_sum, float* __restrict__ accum,
                             int* __restrict__ flag, int* __restrict__ dflag) {
  const int t = threadIdx.x;           // 512 threads
  row_sum[t] = 0.f;
  row_sum[t + 512] = 0.f;
  if (t == 0) *accum = 0.f;

  // ---- input dtype probe (wave 0): ssq of emb row 0 read AS bf16.
  if (t < 64) {
    bf16x8 v = *(const bf16x8*)((const short*)emb + t * 8);
    float s = 0.f;
    #pragma unroll
    for (int j = 0; j < 8; ++j) { float f = bf2f(v[j]); s += f * f; }
    #pragma unroll
    for (int off = 1; off < 64; off <<= 1) s += __shfl_xor(s, off);
    if (t == 0) *dflag = (s < 1e8f) ? 1 : 0;       // NaN/inf compare false -> fp32
  }

  // ---- label width probe: high words if int64 are all zero
  int v = labels[2 * t + 1];
  #pragma unroll
  for (int off = 1; off < 64; off <<= 1) v |= __shfl_xor(v, off);
  __shared__ int red[8];
  if ((t & 63) == 0) red[t >> 6] = v;
  __syncthreads();
  if (t == 0) {
    int o = 0;
    #pragma unroll
    for (int i = 0; i < 8; ++i) o |= red[i];
    *flag = (o == 0) ? 1 : 0;          // 1 => int64 labels (read low word at 2*r)
  }
}

// ---------------- inverse L2 norms + (optional) normalized-bf16 write-back ----------------
// v2: one row per 16 lanes, 128 B of loads per thread (8 independent f32x4) for MLP.
__global__ __launch_bounds__(256) void normconv_kernel(
    const void* __restrict__ emb, const void* __restrict__ wgt,
    const int* __restrict__ dflag,
    float* __restrict__ inv_e, float* __restrict__ inv_w,
    short* __restrict__ An, short* __restrict__ Wn, const int do_conv) {
  const int sub  = threadIdx.x & 15;       // lane within row-group
  const int rloc = threadIdx.x >> 4;       // 0..15 rows per block
  const int row  = blockIdx.x * 16 + rloc;
  int r;
  const void* base;
  float* dst;
  short* out;
  if (row < B_ROWS) { r = row; base = emb; dst = inv_e + row; out = An + (size_t)row * EMB; }
  else {
    r = row - B_ROWS;
    if (r >= NCLS) return;
    base = wgt; dst = inv_w + r; out = Wn + (size_t)r * EMB;
  }
  const int isbf16 = *dflag;
  float f[32];
  if (isbf16) {
    const short* p = (const short*)base + (size_t)r * EMB;
    #pragma unroll
    for (int j = 0; j < 4; ++j) {
      bf16x8 v = *(const bf16x8*)(p + j * 128 + sub * 8);
      #pragma unroll
      for (int t = 0; t < 8; ++t) f[j * 8 + t] = bf2f(v[t]);
    }
  } else {
    const float* p = (const float*)base + (size_t)r * EMB;
    #pragma unroll
    for (int j = 0; j < 8; ++j) {
      f32x4 v = *(const f32x4*)(p + j * 64 + sub * 4);
      #pragma unroll
      for (int t = 0; t < 4; ++t) f[j * 4 + t] = v[t];
    }
  }
  float s = 0.f;
  #pragma unroll
  for (int j = 0; j < 32; ++j) s += f[j] * f[j];
  #pragma unroll
  for (int off = 1; off < 16; off <<= 1) s += __shfl_xor(s, off);
  const float inv = 1.f / fmaxf(sqrtf(s), 1e-12f);
  if (sub == 0) *dst = inv;
  if (do_conv) {
    if (isbf16) {
      #pragma unroll
      for (int j = 0; j < 4; ++j) {
        bf16x8 o;
        #pragma unroll
        for (int t = 0; t < 8; ++t) o[t] = f2bf(f[j * 8 + t] * inv);
        *(bf16x8*)(out + j * 128 + sub * 8) = o;
      }
    } else {
      #pragma unroll
      for (int j = 0; j < 8; ++j) {
        s16x4 o;
        #pragma unroll
        for (int t = 0; t < 4; ++t) o[t] = f2bf(f[j * 4 + t] * inv);
        *(s16x4*)(out + j * 64 + sub * 4) = o;
      }
    }
  }
}

// ---------------- FAST PATH: pure-bf16 NT-GEMM on pre-normalized inputs ----------------
// v2: (a) XCD-grouped block mapping: the 8 M-tiles sharing a W-panel land on one XCD's L2.
//     (b) LDS XOR-swizzle (slot ^= (row>>1)&3) via pre-swizzled global source + swizzled read.
__global__ __launch_bounds__(256, 3) void arc_gemm_fast(
    const short* __restrict__ A, const short* __restrict__ W,
    const int* __restrict__ labels, const int* __restrict__ flag,
    float* __restrict__ row_sum, float* __restrict__ lablogit) {
  // XCD-aware decode: HW assigns flat bid round-robin (XCD = bid & 7).
  // XCD k owns N-panels with ytile%8==k; its j-th block: ytile=(j>>3)*8+k, xtile=j&7.
  const int bid = blockIdx.x;
  const int k   = bid & 7;
  const int j   = bid >> 3;              // 0..783
  const int ytile = (j >> 3) * 8 + k;    // N-panel
  const int xtile = j & 7;               // M-tile
  if (ytile >= NTILES) return;

  __shared__ short As[BM * BK];     // 8 KB, row-major [row][k], row stride 64 B, slot-swizzled
  __shared__ short Bs[BN * BK];     // 8 KB
  __shared__ int   sh_lab[BM];
  __shared__ float sh_sum[BM][2];

  const int tid  = threadIdx.x;
  const int wave = tid >> 6;
  const int lane = tid & 63;
  const int wy = wave >> 1;         // 2x2 wave grid, each wave 64x64
  const int wx = wave & 1;
  const int lr = lane & 15;
  const int lk = lane >> 4;
  const int mBase = xtile * BM;
  const int nBase = ytile * BN;

  const int srow  = lane >> 2;      // staging: 16 rows per wave-instr
  // physical slot (lane&3) at row srow holds logical slot (lane&3)^((srow>>1)&3);
  // (srow>>1)&3 == (lane>>3)&3
  const int sbyte = (((lane & 3) ^ ((lane >> 3) & 3)) << 4);
  const int rswz  = ((lr >> 1) & 3);   // read-side row swizzle term

  f32x4 zero = {0.f, 0.f, 0.f, 0.f};
  f32x4 acc[4][4];
  #pragma unroll
  for (int i = 0; i < 4; ++i)
    #pragma unroll
    for (int jj = 0; jj < 4; ++jj) acc[i][jj] = zero;

  const char* Ab = (const char*)A;   // bf16 row stride 1024 B
  const char* Wb = (const char*)W;

  for (int kc = 0; kc < KCHUNKS; ++kc) {
    __syncthreads();
    const size_t koff = (size_t)kc * 64 + sbyte;
    #pragma unroll
    for (int it = 0; it < 2; ++it) {
      const int c = wave + it * 4;                  // chunk = 16 rows = 1024 B of LDS
      const int ar = mBase + c * 16 + srow;         // always < 1024
      load16(Ab + (size_t)ar * 1024 + koff, (char*)As + (size_t)c * 1024);
      int br = nBase + c * 16 + srow;
      if (br >= NCLS) br = NCLS - 1;                // clamp; masked in epilogue
      load16(Wb + (size_t)br * 1024 + koff, (char*)Bs + (size_t)c * 1024);
    }
    __syncthreads();                                // drains vmcnt/lgkmcnt before use
    bf16x8 af[4], bfr[4];
    #pragma unroll
    for (int mi = 0; mi < 4; ++mi)
      af[mi] = *(const bf16x8*)(As + ((wy * 64 + mi * 16 + lr) * BK + (lk ^ rswz) * 8));
    #pragma unroll
    for (int ni = 0; ni < 4; ++ni)
      bfr[ni] = *(const bf16x8*)(Bs + ((wx * 64 + ni * 16 + lr) * BK + (lk ^ rswz) * 8));
    #pragma unroll
    for (int mi = 0; mi < 4; ++mi)
      #pragma unroll
      for (int ni = 0; ni < 4; ++ni)
        acc[mi][ni] = __builtin_amdgcn_mfma_f32_16x16x32_bf16(af[mi], bfr[ni], acc[mi][ni], 0, 0, 0);
  }

  // ---- epilogue (cos = accumulator directly; inputs pre-normalized) ----
  __syncthreads();
  if (tid < BM) {
    const int r = mBase + tid;
    const int f = *flag;
    sh_lab[tid] = labels[f ? (size_t)(2 * r) : (size_t)r];
  }
  __syncthreads();

  #pragma unroll
  for (int mi = 0; mi < 4; ++mi) {
    #pragma unroll
    for (int reg = 0; reg < 4; ++reg) {
      const int lrow = wy * 64 + mi * 16 + lk * 4 + reg;   // C/D: row=(lane>>4)*4+reg
      const int grow = mBase + lrow;
      const int lab = sh_lab[lrow];
      float s = 0.f;
      #pragma unroll
      for (int ni = 0; ni < 4; ++ni) {
        const int gcol = nBase + wx * 64 + ni * 16 + lr;   // C/D: col=lane&15
        if (gcol < NCLS) {
          const float cosv = acc[mi][ni][reg];
          float logit;
          if (gcol == lab) {
            const float sine = sqrtf(fmaxf(1.f - cosv * cosv, 0.f));
            float phi = cosv * COS_M - sine * SIN_M;
            phi = (cosv > TH_C) ? phi : (cosv - MM_C);
            logit = SCALE_ * phi;
            lablogit[grow] = logit;                        // unique writer grid-wide
          } else {
            logit = SCALE_ * cosv;
          }
          s += __expf(logit - SCALE_);                     // offset-64 softmax partial
        }
      }
      #pragma unroll
      for (int off = 1; off < 16; off <<= 1) s += __shfl_xor(s, off);
      if (lr == 0) sh_sum[lrow][wx] = s;
    }
  }
  __syncthreads();
  if (tid < BM)
    atomicAdd(&row_sum[mBase + tid], sh_sum[tid][0] + sh_sum[tid][1]);
}

// ---------------- FALLBACK: fused NT-GEMM with in-loop dtype staging ----------------
__global__ __launch_bounds__(256, 3) void arc_gemm(
    const void* __restrict__ A, const void* __restrict__ W,
    const float* __restrict__ inv_e, const float* __restrict__ inv_w,
    const int* __restrict__ labels, const int* __restrict__ flag,
    const int* __restrict__ dflag,
    float* __restrict__ row_sum, float* __restrict__ lablogit) {
  __shared__ short As[BM * BK];
  __shared__ short Bs[BN * BK];
  __shared__ int   sh_lab[BM];
  __shared__ float sh_sum[BM][2];

  const int tid  = threadIdx.x;
  const int wave = tid >> 6;
  const int lane = tid & 63;
  const int wy = wave >> 1;
  const int wx = wave & 1;
  const int lr = lane & 15;
  const int lk = lane >> 4;
  const int mBase = blockIdx.x * BM;
  const int nBase = blockIdx.y * BN;
  const int isbf16 = *dflag;

  const int srow  = lane >> 2;
  const int sbyte = (lane & 3) * 16;

  f32x4 zero = {0.f, 0.f, 0.f, 0.f};
  f32x4 acc[4][4];
  #pragma unroll
  for (int i = 0; i < 4; ++i)
    #pragma unroll
    for (int j = 0; j < 4; ++j) acc[i][j] = zero;

  const char*  Ab = (const char*)A;
  const char*  Wb = (const char*)W;
  const float* Af = (const float*)A;
  const float* Wf = (const float*)W;

  for (int kc = 0; kc < KCHUNKS; ++kc) {
    __syncthreads();
    if (isbf16) {
      const size_t koff = (size_t)kc * 64 + sbyte;
      #pragma unroll
      for (int it = 0; it < 2; ++it) {
        const int c = wave + it * 4;
        const int ar = mBase + c * 16 + srow;
        load16(Ab + (size_t)ar * 1024 + koff, (char*)As + (size_t)c * 1024);
        int br = nBase + c * 16 + srow;
        if (br >= NCLS) br = NCLS - 1;
        load16(Wb + (size_t)br * 1024 + koff, (char*)Bs + (size_t)c * 1024);
      }
    } else {
      #pragma unroll
      for (int p = 0; p < 2; ++p) {
        const int u   = p * 256 + tid;
        const int row = u >> 2;
        const int seg = u & 3;
        const float* ga = Af + ((size_t)(mBase + row) * EMB + kc * 32 + seg * 8);
        f32x4 x = *(const f32x4*)ga;
        f32x4 y = *(const f32x4*)(ga + 4);
        bf16x8 tpack;
        #pragma unroll
        for (int j = 0; j < 4; ++j) { tpack[j] = f2bf(x[j]); tpack[j + 4] = f2bf(y[j]); }
        *(bf16x8*)(As + row * BK + seg * 8) = tpack;
        int br = nBase + row;
        if (br >= NCLS) br = NCLS - 1;
        const float* gb = Wf + ((size_t)br * EMB + kc * 32 + seg * 8);
        x = *(const f32x4*)gb;
        y = *(const f32x4*)(gb + 4);
        #pragma unroll
        for (int j = 0; j < 4; ++j) { tpack[j] = f2bf(x[j]); tpack[j + 4] = f2bf(y[j]); }
        *(bf16x8*)(Bs + row * BK + seg * 8) = tpack;
      }
    }
    __syncthreads();
    bf16x8 af[4], bfr[4];
    #pragma unroll
    for (int mi = 0; mi < 4; ++mi)
      af[mi] = *(const bf16x8*)(As + ((wy * 64 + mi * 16 + lr) * BK + lk * 8));
    #pragma unroll
    for (int ni = 0; ni < 4; ++ni)
      bfr[ni] = *(const bf16x8*)(Bs + ((wx * 64 + ni * 16 + lr) * BK + lk * 8));
    #pragma unroll
    for (int mi = 0; mi < 4; ++mi)
      #pragma unroll
      for (int ni = 0; ni < 4; ++ni)
        acc[mi][ni] = __builtin_amdgcn_mfma_f32_16x16x32_bf16(af[mi], bfr[ni], acc[mi][ni], 0, 0, 0);
  }

  __syncthreads();
  if (tid < BM) {
    const int r = mBase + tid;
    const int f = *flag;
    sh_lab[tid] = labels[f ? (size_t)(2 * r) : (size_t)r];
  }
  __syncthreads();

  #pragma unroll
  for (int mi = 0; mi < 4; ++mi) {
    #pragma unroll
    for (int reg = 0; reg < 4; ++reg) {
      const int lrow = wy * 64 + mi * 16 + lk * 4 + reg;
      const int grow = mBase + lrow;
      const float ie = inv_e[grow];
      const int lab = sh_lab[lrow];
      float s = 0.f;
      #pragma unroll
      for (int ni = 0; ni < 4; ++ni) {
        const int gcol = nBase + wx * 64 + ni * 16 + lr;
        if (gcol < NCLS) {
          const float cosv = acc[mi][ni][reg] * ie * inv_w[gcol];
          float logit;
          if (gcol == lab) {
            const float sine = sqrtf(fmaxf(1.f - cosv * cosv, 0.f));
            float phi = cosv * COS_M - sine * SIN_M;
            phi = (cosv > TH_C) ? phi : (cosv - MM_C);
            logit = SCALE_ * phi;
            lablogit[grow] = logit;
          } else {
            logit = SCALE_ * cosv;
          }
          s += __expf(logit - SCALE_);
        }
      }
      #pragma unroll
      for (int off = 1; off < 16; off <<= 1) s += __shfl_xor(s, off);
      if (lr == 0) sh_sum[lrow][wx] = s;
    }
  }
  __syncthreads();
  if (tid < BM)
    atomicAdd(&row_sum[mBase + tid], sh_sum[tid][0] + sh_sum[tid][1]);
}

// ---------------- per-row loss -> mean ----------------
__global__ void loss_kernel(const float* __restrict__ row_sum,
                            const float* __restrict__ lablogit,
                            float* __restrict__ accum) {
  const int r = blockIdx.x * 128 + threadIdx.x;
  float loss = SCALE_ + logf(row_sum[r]) - lablogit[r];
  #pragma unroll
  for (int off = 1; off < 64; off <<= 1) loss += __shfl_xor(loss, off);
  __shared__ float rs[2];
  if ((threadIdx.x & 63) == 0) rs[threadIdx.x >> 6] = loss;
  __syncthreads();
  if (threadIdx.x == 0) atomicAdd(accum, rs[0] + rs[1]);
}

__global__ void finalize_kernel(const float* __restrict__ accum, float* __restrict__ out) {
  out[0] = accum[0] * (1.0f / 1024.0f);   // reference output is float32
}

// ---------------- launch ----------------
extern "C" void kernel_launch(void* const* d_in, const int* in_sizes, int n_in,
                              void* d_out, int out_size, void* d_ws, size_t ws_size,
                              hipStream_t stream) {
  const void* emb   = d_in[0];          // [1024][512]  bf16 or fp32 (auto-detected)
  const void* wgt   = d_in[1];          // [100000][512]
  const int* labels = (const int*)d_in[2];   // int32 or int64 (auto-detected)
  float* out = (float*)d_out;

  const int NORM_BLOCKS = (B_ROWS + NCLS + 15) / 16;   // 16 rows/block

  // fast-path workspace: pre-normalized bf16 copies of W and A
  const size_t WN_SHORTS = (size_t)NCLS * EMB;        // 51,200,000
  const size_t AN_SHORTS = (size_t)B_ROWS * EMB;      // 524,288
  const size_t FAST_NEED = (WN_SHORTS + AN_SHORTS) * 2 + 103075u * 4;  // ~103.9 MB

  if (ws_size >= FAST_NEED) {
    short* Wn = (short*)d_ws;
    short* An = Wn + WN_SHORTS;
    float* tail     = (float*)(An + AN_SHORTS);
    float* inv_e    = tail;               // 1024 (unused by fast gemm; kept for fallback parity)
    float* inv_w    = tail + 1024;        // 100000
    float* lablogit = tail + 101024;      // 1024
    float* row_sum  = tail + 102048;      // 1024
    float* accum    = tail + 103072;      // 1
    int*   flag     = (int*)(tail + 103073);
    int*   dflag    = (int*)(tail + 103074);

    setup_kernel<<<1, 512, 0, stream>>>(emb, labels, row_sum, accum, flag, dflag);
    normconv_kernel<<<NORM_BLOCKS, 256, 0, stream>>>(
        emb, wgt, dflag, inv_e, inv_w, An, Wn, 1);
    // 8 XCDs x 784 blocks each (ceil(782/8)*8 y-groups x 8 x-tiles); 16 no-op blocks
    arc_gemm_fast<<<8 * 784, 256, 0, stream>>>(An, Wn, labels, flag, row_sum, lablogit);
    loss_kernel<<<8, 128, 0, stream>>>(row_sum, lablogit, accum);
    finalize_kernel<<<1, 1, 0, stream>>>(accum, out);
  } else {
    float* ws       = (float*)d_ws;
    float* inv_e    = ws;                 // 1024
    float* inv_w    = ws + 1024;          // 100000
    float* lablogit = ws + 101024;        // 1024
    float* row_sum  = ws + 102048;        // 1024
    float* accum    = ws + 103072;        // 1
    int*   flag     = (int*)(ws + 103073);
    int*   dflag    = (int*)(ws + 103074);

    setup_kernel<<<1, 512, 0, stream>>>(emb, labels, row_sum, accum, flag, dflag);
    normconv_kernel<<<NORM_BLOCKS, 256, 0, stream>>>(
        emb, wgt, dflag, inv_e, inv_w, (short*)inv_e, (short*)inv_e, 0);
    dim3 grid(8, NTILES);
    arc_gemm<<<grid, 256, 0, stream>>>(emb, wgt, inv_e, inv_w, labels, flag, dflag, row_sum, lablogit);
    loss_kernel<<<8, 128, 0, stream>>>(row_sum, lablogit, accum);
    finalize_kernel<<<1, 1, 0, stream>>>(accum, out);
  }
}